// Round 1
// baseline (3402.068 us; speedup 1.0000x reference)
//
#include <hip/hip_runtime.h>
#include <hip/hip_bf16.h>
#include <math.h>

// ---------------------------------------------------------------------------
// Show-Attend-Tell style LSTM decoder, fp32 baseline.
// B=64, P=196, E_ENC=2048, A=E_EMB=D=512, V=10000, T_DEC=20.
//
// Decomposition:
//   preamble: k_order (stable sort by -len), k_mean, k_h0c0, k_encatt (big GEMM)
//   per step: S1 splitK GEMM h@[att_dec_W|sig_W|lstm_Whh]^T -> Zp partials
//             k_att_softmax (att2+e+softmax+alpha, one block per b)
//             k_ctx_x      (ctx, gate, x assembly)
//             S4 splitK GEMM x@lstm_Wih^T -> Gp partials
//             k_cell       (sum partials + biases, LSTM cell, ping-pong h/c)
//             k_gemm_final (preds = h_new@fc_W^T + fc_b, masked write)
// Split-K uses per-split partial buffers (no atomics, no init kernels);
// consumers sum the partials. h/c masking is skipped deliberately: inactive
// rows never influence any unmasked output (outputs are masked to 0).
// ---------------------------------------------------------------------------

#define BB 64
#define PP 196
#define EE 2048
#define AA 512
#define DD 512
#define VV 10000
#define TT 20
#define XX 2560          // E_EMB(512) + E_ENC(2048)
#define NCAT 4608        // AA(att2) + 2048(gatepre) + 2048(gates_hh)
#define S1_SPLITS 4
#define S4_SPLITS 8

// -------------------------------- preamble ---------------------------------

__global__ void k_order(const int* __restrict__ cap_len,
                        int* __restrict__ order, int* __restrict__ declen) {
  __shared__ int len[BB];
  int i = threadIdx.x;
  len[i] = cap_len[i];
  __syncthreads();
  int key = (64 - len[i]) * 64 + i;      // descending len, stable (ties by i)
  int rank = 0;
  for (int j = 0; j < BB; ++j) {
    int kj = (64 - len[j]) * 64 + j;
    rank += (kj < key);
  }
  order[rank] = i;
  declen[rank] = len[i] - 1;
}

__global__ __launch_bounds__(256) void k_mean(const float* __restrict__ enc,
                                              const int* __restrict__ order,
                                              float* __restrict__ mean) {
  int b = blockIdx.x;
  int e = blockIdx.y * 256 + threadIdx.x;
  const float* src = enc + ((size_t)order[b] * PP) * EE + e;
  float s = 0.f;
#pragma unroll 4
  for (int p = 0; p < PP; ++p) s += src[(size_t)p * EE];
  mean[(size_t)b * EE + e] = s * (1.0f / PP);
}

__global__ __launch_bounds__(256) void k_h0c0(
    const float* __restrict__ mean, const float* __restrict__ hW,
    const float* __restrict__ hb, const float* __restrict__ cW,
    const float* __restrict__ cb, float* __restrict__ h, float* __restrict__ c) {
  int b = blockIdx.x;
  __shared__ float m[EE];
  for (int e = threadIdx.x; e < EE; e += 256) m[e] = mean[(size_t)b * EE + e];
  __syncthreads();
  for (int d = threadIdx.x; d < DD; d += 256) {
    const float4* wr = (const float4*)(hW + (size_t)d * EE);
    const float4* wc = (const float4*)(cW + (size_t)d * EE);
    float sh = 0.f, sc = 0.f;
    for (int e4 = 0; e4 < EE / 4; ++e4) {
      float4 mv = *(const float4*)&m[e4 * 4];
      float4 wv = wr[e4];
      sh += mv.x * wv.x + mv.y * wv.y + mv.z * wv.z + mv.w * wv.w;
      float4 cv = wc[e4];
      sc += mv.x * cv.x + mv.y * cv.y + mv.z * cv.z + mv.w * cv.w;
    }
    h[(size_t)b * DD + d] = sh + hb[d];
    c[(size_t)b * DD + d] = sc + cb[d];
  }
}

// enc_att[m][n] = sum_k enc_sorted[m][k] * W[n][k] + bias[n]
// M=12544 (=64*196 gathered rows), N=512, K=2048. BM=128, BN=64, BK=32.
__global__ __launch_bounds__(256) void k_encatt(
    const float* __restrict__ enc, const int* __restrict__ order,
    const float* __restrict__ W, const float* __restrict__ bias,
    float* __restrict__ out) {
  __shared__ float As[32][132];   // k-major, stride mult of 4 for b128 reads
  __shared__ float Bs[32][68];
  const int tid = threadIdx.x;
  const int tx = tid & 15, ty = tid >> 4;
  const int m0 = blockIdx.x * 128;
  const int n0 = blockIdx.y * 64;
  const int arow = tid >> 3;        // 0..31
  const int acol = (tid & 7) * 4;   // 0..28
  const int brow = tid >> 2;        // 0..63
  const int bcol = (tid & 3) * 8;
  const float* arp[4];
#pragma unroll
  for (int q = 0; q < 4; ++q) {
    int m = m0 + arow + 32 * q;
    int bb = m / PP;
    int p = m - bb * PP;
    arp[q] = enc + ((size_t)order[bb] * PP + p) * EE + acol;
  }
  const float* brp = W + (size_t)(n0 + brow) * EE + bcol;
  float acc[8][4] = {};
  for (int k0 = 0; k0 < EE; k0 += 32) {
#pragma unroll
    for (int q = 0; q < 4; ++q) {
      float4 v = *(const float4*)(arp[q] + k0);
      int r = arow + 32 * q;
      As[acol + 0][r] = v.x; As[acol + 1][r] = v.y;
      As[acol + 2][r] = v.z; As[acol + 3][r] = v.w;
    }
    {
      float4 v0 = *(const float4*)(brp + k0);
      float4 v1 = *(const float4*)(brp + k0 + 4);
      Bs[bcol + 0][brow] = v0.x; Bs[bcol + 1][brow] = v0.y;
      Bs[bcol + 2][brow] = v0.z; Bs[bcol + 3][brow] = v0.w;
      Bs[bcol + 4][brow] = v1.x; Bs[bcol + 5][brow] = v1.y;
      Bs[bcol + 6][brow] = v1.z; Bs[bcol + 7][brow] = v1.w;
    }
    __syncthreads();
#pragma unroll
    for (int k = 0; k < 32; ++k) {
      float a8[8], b4[4];
      *(float4*)&a8[0] = *(const float4*)&As[k][ty * 8];
      *(float4*)&a8[4] = *(const float4*)&As[k][ty * 8 + 4];
      *(float4*)&b4[0] = *(const float4*)&Bs[k][tx * 4];
#pragma unroll
      for (int i = 0; i < 8; ++i)
#pragma unroll
        for (int j = 0; j < 4; ++j) acc[i][j] += a8[i] * b4[j];
    }
    __syncthreads();
  }
  float4 bv = *(const float4*)&bias[n0 + tx * 4];
#pragma unroll
  for (int i = 0; i < 8; ++i) {
    int m = m0 + ty * 8 + i;
    float4 v;
    v.x = acc[i][0] + bv.x; v.y = acc[i][1] + bv.y;
    v.z = acc[i][2] + bv.z; v.w = acc[i][3] + bv.w;
    *(float4*)(out + (size_t)m * AA + n0 + tx * 4) = v;
  }
}

// ------------------------- per-step split-K GEMM ---------------------------
// out_partial[split][m][n0+n] = sum_{k in split} A[m][k] * Wsel[n][k]
// A is 64 x lda (lda == K). W selected from up to 3 concatenated matrices by n0.
__global__ __launch_bounds__(256) void k_gemm_partial(
    const float* __restrict__ A, int lda, const float* __restrict__ W0,
    const float* __restrict__ W1, const float* __restrict__ W2, int nb1,
    int nb2, int kchunks, float* __restrict__ outp, int ldo) {
  __shared__ float As[32][68];
  __shared__ float Bs[32][68];
  const int tid = threadIdx.x;
  const int tx = tid & 15, ty = tid >> 4;
  const int n0 = blockIdx.x * 64;
  const int split = blockIdx.y;
  const int kbase = split * kchunks * 32;
  const float* wbase; int nrel;
  if (n0 < nb1)      { wbase = W0; nrel = n0; }
  else if (n0 < nb2) { wbase = W1; nrel = n0 - nb1; }
  else               { wbase = W2; nrel = n0 - nb2; }
  const int arow = tid >> 2;
  const int acol = (tid & 3) * 8;
  const float* aptr = A + (size_t)arow * lda + kbase + acol;
  const float* bptr = wbase + (size_t)(nrel + arow) * lda + kbase + acol;
  float acc[4][4] = {};
  for (int kc = 0; kc < kchunks; ++kc) {
    float4 av0 = *(const float4*)(aptr);
    float4 av1 = *(const float4*)(aptr + 4);
    float4 bv0 = *(const float4*)(bptr);
    float4 bv1 = *(const float4*)(bptr + 4);
    aptr += 32; bptr += 32;
    As[acol + 0][arow] = av0.x; As[acol + 1][arow] = av0.y;
    As[acol + 2][arow] = av0.z; As[acol + 3][arow] = av0.w;
    As[acol + 4][arow] = av1.x; As[acol + 5][arow] = av1.y;
    As[acol + 6][arow] = av1.z; As[acol + 7][arow] = av1.w;
    Bs[acol + 0][arow] = bv0.x; Bs[acol + 1][arow] = bv0.y;
    Bs[acol + 2][arow] = bv0.z; Bs[acol + 3][arow] = bv0.w;
    Bs[acol + 4][arow] = bv1.x; Bs[acol + 5][arow] = bv1.y;
    Bs[acol + 6][arow] = bv1.z; Bs[acol + 7][arow] = bv1.w;
    __syncthreads();
#pragma unroll
    for (int k = 0; k < 32; ++k) {
      float4 ra = *(const float4*)&As[k][ty * 4];
      float4 rb = *(const float4*)&Bs[k][tx * 4];
      acc[0][0] += ra.x * rb.x; acc[0][1] += ra.x * rb.y;
      acc[0][2] += ra.x * rb.z; acc[0][3] += ra.x * rb.w;
      acc[1][0] += ra.y * rb.x; acc[1][1] += ra.y * rb.y;
      acc[1][2] += ra.y * rb.z; acc[1][3] += ra.y * rb.w;
      acc[2][0] += ra.z * rb.x; acc[2][1] += ra.z * rb.y;
      acc[2][2] += ra.z * rb.z; acc[2][3] += ra.z * rb.w;
      acc[3][0] += ra.w * rb.x; acc[3][1] += ra.w * rb.y;
      acc[3][2] += ra.w * rb.z; acc[3][3] += ra.w * rb.w;
    }
    __syncthreads();
  }
  float* obase = outp + ((size_t)split * BB) * ldo + n0 + tx * 4;
#pragma unroll
  for (int i = 0; i < 4; ++i) {
    int m = ty * 4 + i;
    float4 v;
    v.x = acc[i][0]; v.y = acc[i][1]; v.z = acc[i][2]; v.w = acc[i][3];
    *(float4*)(obase + (size_t)m * ldo) = v;
  }
}

// ------------------------------ attention ----------------------------------

__global__ __launch_bounds__(256) void k_att_softmax(
    const float* __restrict__ eatt, const float* __restrict__ Zp,
    const float* __restrict__ adb, const float* __restrict__ afW,
    const float* __restrict__ afb, const int* __restrict__ declen,
    float* __restrict__ alph, float* __restrict__ alphas, int t) {
  int b = blockIdx.x;
  __shared__ float att2[AA];
  __shared__ float wf[AA];
  __shared__ float esm[PP];
  __shared__ float red[16];
  for (int a = threadIdx.x; a < AA; a += 256) {
    float s = adb[a];
#pragma unroll
    for (int sp = 0; sp < S1_SPLITS; ++sp)
      s += Zp[((size_t)sp * BB + b) * NCAT + a];
    att2[a] = s;
    wf[a] = afW[a];
  }
  __syncthreads();
  int lane = threadIdx.x & 63;
  int w = threadIdx.x >> 6;
  for (int p = w; p < PP; p += 4) {
    const float4* r4 =
        (const float4*)(eatt + ((size_t)b * PP + p) * AA + lane * 8);
    float4 v0 = r4[0], v1 = r4[1];
    float vv[8] = {v0.x, v0.y, v0.z, v0.w, v1.x, v1.y, v1.z, v1.w};
    const float* a2 = &att2[lane * 8];
    const float* wv = &wf[lane * 8];
    float s = 0.f;
#pragma unroll
    for (int j = 0; j < 8; ++j) {
      float u = vv[j] + a2[j];
      u = u > 0.f ? u : 0.f;
      s += u * wv[j];
    }
#pragma unroll
    for (int off = 32; off; off >>= 1) s += __shfl_xor(s, off);
    if (lane == 0) esm[p] = s + afb[0];
  }
  __syncthreads();
  float v = (threadIdx.x < PP) ? esm[threadIdx.x] : -3.4e38f;
  float m = v;
#pragma unroll
  for (int off = 32; off; off >>= 1) m = fmaxf(m, __shfl_xor(m, off));
  if (lane == 0) red[w] = m;
  __syncthreads();
  m = fmaxf(fmaxf(red[0], red[1]), fmaxf(red[2], red[3]));
  float ex = (threadIdx.x < PP) ? __expf(v - m) : 0.f;
  float ssum = ex;
#pragma unroll
  for (int off = 32; off; off >>= 1) ssum += __shfl_xor(ssum, off);
  if (lane == 0) red[8 + w] = ssum;
  __syncthreads();
  float tot = red[8] + red[9] + red[10] + red[11];
  if (threadIdx.x < PP) {
    float a_ = ex / tot;
    alph[(size_t)b * PP + threadIdx.x] = a_;
    bool act = t < declen[b];
    alphas[((size_t)b * TT + t) * PP + threadIdx.x] = act ? a_ : 0.f;
  }
}

__global__ __launch_bounds__(256) void k_ctx_x(
    const float* __restrict__ enc, const int* __restrict__ order,
    const float* __restrict__ alph, const float* __restrict__ Zp,
    const float* __restrict__ sb, const float* __restrict__ embW,
    const int* __restrict__ cap, float* __restrict__ x, int t) {
  int b = blockIdx.x;
  __shared__ float al[PP];
  for (int p = threadIdx.x; p < PP; p += 256) al[p] = alph[(size_t)b * PP + p];
  __syncthreads();
  int e = blockIdx.y * 256 + threadIdx.x;
  const float* ep = enc + ((size_t)order[b] * PP) * EE + e;
  float s = 0.f;
#pragma unroll 4
  for (int p = 0; p < PP; ++p) s += al[p] * ep[(size_t)p * EE];
  float g = sb[e];
#pragma unroll
  for (int sp = 0; sp < S1_SPLITS; ++sp)
    g += Zp[((size_t)sp * BB + b) * NCAT + AA + e];
  g = 1.f / (1.f + __expf(-g));
  x[(size_t)b * XX + 512 + e] = g * s;
  if (blockIdx.y == 0) {
    int tok = cap[order[b] * 21 + t];
    for (int i = threadIdx.x; i < 512; i += 256)
      x[(size_t)b * XX + i] = embW[(size_t)tok * 512 + i];
  }
}

// ------------------------------- LSTM cell ---------------------------------

__global__ __launch_bounds__(256) void k_cell(
    const float* __restrict__ Zp, const float* __restrict__ Gp,
    const float* __restrict__ bih, const float* __restrict__ bhh,
    const float* __restrict__ cin, float* __restrict__ hout,
    float* __restrict__ cout) {
  int idx = blockIdx.x * 256 + threadIdx.x;   // 0..32767
  int b = idx >> 9, d = idx & 511;
  float g4[4];
#pragma unroll
  for (int q = 0; q < 4; ++q) {
    int j = q * 512 + d;
    float s = bih[j] + bhh[j];
#pragma unroll
    for (int sp = 0; sp < S1_SPLITS; ++sp)
      s += Zp[((size_t)sp * BB + b) * NCAT + 2560 + j];
#pragma unroll
    for (int sp = 0; sp < S4_SPLITS; ++sp)
      s += Gp[((size_t)sp * BB + b) * 2048 + j];
    g4[q] = s;
  }
  float ig = 1.f / (1.f + __expf(-g4[0]));
  float fg = 1.f / (1.f + __expf(-g4[1]));
  float gg = tanhf(g4[2]);
  float og = 1.f / (1.f + __expf(-g4[3]));
  float c = fg * cin[(size_t)b * DD + d] + ig * gg;
  float h = og * tanhf(c);
  cout[(size_t)b * DD + d] = c;
  hout[(size_t)b * DD + d] = h;
}

// --------------------------- final fc (preds) ------------------------------

__global__ __launch_bounds__(256) void k_gemm_final(
    const float* __restrict__ A, const float* __restrict__ W,
    const float* __restrict__ bias, const int* __restrict__ declen, int t,
    float* __restrict__ out) {
  __shared__ float As[32][68];
  __shared__ float Bs[32][68];
  const int tid = threadIdx.x;
  const int tx = tid & 15, ty = tid >> 4;
  const int n0 = blockIdx.x * 64;
  const int arow = tid >> 2;
  const int acol = (tid & 3) * 8;
  const float* aptr = A + (size_t)arow * DD + acol;
  const int wrow = n0 + arow;
  const bool bok = (wrow < VV);
  const float* bptr = W + (size_t)(bok ? wrow : 0) * DD + acol;
  float acc[4][4] = {};
  for (int kc = 0; kc < 16; ++kc) {
    float4 av0 = *(const float4*)(aptr);
    float4 av1 = *(const float4*)(aptr + 4);
    float4 bv0, bv1;
    if (bok) {
      bv0 = *(const float4*)(bptr);
      bv1 = *(const float4*)(bptr + 4);
    } else {
      bv0.x = bv0.y = bv0.z = bv0.w = 0.f;
      bv1 = bv0;
    }
    aptr += 32; bptr += 32;
    As[acol + 0][arow] = av0.x; As[acol + 1][arow] = av0.y;
    As[acol + 2][arow] = av0.z; As[acol + 3][arow] = av0.w;
    As[acol + 4][arow] = av1.x; As[acol + 5][arow] = av1.y;
    As[acol + 6][arow] = av1.z; As[acol + 7][arow] = av1.w;
    Bs[acol + 0][arow] = bv0.x; Bs[acol + 1][arow] = bv0.y;
    Bs[acol + 2][arow] = bv0.z; Bs[acol + 3][arow] = bv0.w;
    Bs[acol + 4][arow] = bv1.x; Bs[acol + 5][arow] = bv1.y;
    Bs[acol + 6][arow] = bv1.z; Bs[acol + 7][arow] = bv1.w;
    __syncthreads();
#pragma unroll
    for (int k = 0; k < 32; ++k) {
      float4 ra = *(const float4*)&As[k][ty * 4];
      float4 rb = *(const float4*)&Bs[k][tx * 4];
      acc[0][0] += ra.x * rb.x; acc[0][1] += ra.x * rb.y;
      acc[0][2] += ra.x * rb.z; acc[0][3] += ra.x * rb.w;
      acc[1][0] += ra.y * rb.x; acc[1][1] += ra.y * rb.y;
      acc[1][2] += ra.y * rb.z; acc[1][3] += ra.y * rb.w;
      acc[2][0] += ra.z * rb.x; acc[2][1] += ra.z * rb.y;
      acc[2][2] += ra.z * rb.z; acc[2][3] += ra.z * rb.w;
      acc[3][0] += ra.w * rb.x; acc[3][1] += ra.w * rb.y;
      acc[3][2] += ra.w * rb.z; acc[3][3] += ra.w * rb.w;
    }
    __syncthreads();
  }
#pragma unroll
  for (int i = 0; i < 4; ++i) {
    int m = ty * 4 + i;
    bool act = t < declen[m];
#pragma unroll
    for (int j = 0; j < 4; ++j) {
      int n = n0 + tx * 4 + j;
      if (n < VV)
        out[(size_t)m * (TT * VV) + n] = act ? (acc[i][j] + bias[n]) : 0.f;
    }
  }
}

// ------------------------------ launch -------------------------------------

extern "C" void kernel_launch(void* const* d_in, const int* in_sizes, int n_in,
                              void* d_out, int out_size, void* d_ws,
                              size_t ws_size, hipStream_t stream) {
  (void)in_sizes; (void)n_in; (void)out_size; (void)ws_size;
  const float* enc  = (const float*)d_in[0];
  const float* embW = (const float*)d_in[1];
  const float* hW   = (const float*)d_in[2];
  const float* hb   = (const float*)d_in[3];
  const float* cW   = (const float*)d_in[4];
  const float* cb   = (const float*)d_in[5];
  const float* aeW  = (const float*)d_in[6];
  const float* aeb  = (const float*)d_in[7];
  const float* adW  = (const float*)d_in[8];
  const float* adb  = (const float*)d_in[9];
  const float* afW  = (const float*)d_in[10];
  const float* afb  = (const float*)d_in[11];
  const float* sW   = (const float*)d_in[12];
  const float* sb   = (const float*)d_in[13];
  const float* Wih  = (const float*)d_in[14];
  const float* Whh  = (const float*)d_in[15];
  const float* bih  = (const float*)d_in[16];
  const float* bhh  = (const float*)d_in[17];
  const float* fcW  = (const float*)d_in[18];
  const float* fcb  = (const float*)d_in[19];
  const int*   cap  = (const int*)d_in[20];
  const int*   capl = (const int*)d_in[21];

  int* order  = (int*)d_ws;
  int* declen = order + 64;
  float* wsf  = (float*)((char*)d_ws + 512);
  float* mean = wsf;                                   // 64*2048
  float* hbuf = mean + (size_t)BB * EE;                // 2*64*512 ping-pong
  float* cbuf = hbuf + 2 * BB * DD;                    // 2*64*512
  float* eatt = cbuf + 2 * BB * DD;                    // 64*196*512
  float* Zp   = eatt + (size_t)BB * PP * AA;           // 4*64*4608
  float* Gp   = Zp + (size_t)S1_SPLITS * BB * NCAT;    // 8*64*2048
  float* alph = Gp + (size_t)S4_SPLITS * BB * 2048;    // 64*196
  float* xbuf = alph + BB * PP;                        // 64*2560
  // total ws: ~36.4 MB

  float* preds  = (float*)d_out;                       // 64*20*10000
  float* alphas = preds + (size_t)BB * TT * VV;        // 64*20*196

  k_order<<<1, 64, 0, stream>>>(capl, order, declen);
  k_mean<<<dim3(BB, EE / 256), 256, 0, stream>>>(enc, order, mean);
  k_h0c0<<<BB, 256, 0, stream>>>(mean, hW, hb, cW, cb, hbuf, cbuf);
  k_encatt<<<dim3((BB * PP) / 128, AA / 64), 256, 0, stream>>>(enc, order, aeW,
                                                               aeb, eatt);

  for (int t = 0; t < TT; ++t) {
    const float* hin = hbuf + (t & 1) * BB * DD;
    const float* cin = cbuf + (t & 1) * BB * DD;
    float* hout = hbuf + ((t + 1) & 1) * BB * DD;
    float* cout = cbuf + ((t + 1) & 1) * BB * DD;
    // S1: Z = h @ [att_dec_W | sig_W | lstm_Whh]^T  (K=512, 4 splits x 4 chunks)
    k_gemm_partial<<<dim3(NCAT / 64, S1_SPLITS), 256, 0, stream>>>(
        hin, 512, adW, sW, Whh, 512, 2560, 4, Zp, NCAT);
    k_att_softmax<<<BB, 256, 0, stream>>>(eatt, Zp, adb, afW, afb, declen,
                                          alph, alphas, t);
    k_ctx_x<<<dim3(BB, EE / 256), 256, 0, stream>>>(enc, order, alph, Zp, sb,
                                                    embW, cap, xbuf, t);
    // S4: x @ lstm_Wih^T  (K=2560, 8 splits x 10 chunks)
    k_gemm_partial<<<dim3(2048 / 64, S4_SPLITS), 256, 0, stream>>>(
        xbuf, XX, Wih, Wih, Wih, 1 << 30, 1 << 30, 10, Gp, 2048);
    k_cell<<<(BB * DD) / 256, 256, 0, stream>>>(Zp, Gp, bih, bhh, cin, hout,
                                                cout);
    k_gemm_final<<<dim3((VV + 63) / 64), 256, 0, stream>>>(hout, fcW, fcb,
                                                           declen, t,
                                                           preds + (size_t)t * VV);
  }
}

// Round 2
// 2109.014 us; speedup vs baseline: 1.6131x; 1.6131x over previous
//
#include <hip/hip_runtime.h>
#include <hip/hip_bf16.h>
#include <math.h>

// ---------------------------------------------------------------------------
// Show-Attend-Tell LSTM decoder, round 2: bf16 MFMA everywhere matmul-shaped.
// B=64, P=196, E_ENC=2048, A=E_EMB=D=512, V=10000, T_DEC=20.
//
//   preamble: k_order, k_enc_conv (gather+sort enc -> bf16, + mean),
//             k_h0c0, 6x k_f2b8 weight converts, k_gemm_big<0> (enc_att, MFMA)
//   per step: k_skinny  S1: Z = h @ [att_dec_W|sig_W|lstm_Whh]^T  (bf16 MFMA)
//             k_att     att2+e+softmax -> alpha (+masked alphas out)
//             k_ctx     ctx (bf16 enc) + gate + x assembly (bf16)
//             k_skinny  S4: x @ lstm_Wih^T, split-K=4 -> Gp partials
//             k_cell    gates sum + LSTM cell; c fp32, h -> bf16 h_all[t+1]
//   end:      k_gemm_big<1>  preds = h_all[1..20] @ fc_W^T  (one batched MFMA)
//
// LDS discipline (T2/T3): global_load_lds writes LINEAR dest; the 16B-slot
// XOR swizzle (slot ^= (row>>1)&3) is applied to the per-lane GLOBAL source
// on stage and to the ds_read address on consume (both-sides-or-neither).
// ---------------------------------------------------------------------------

#define BB 64
#define PP 196
#define EE 2048
#define AA 512
#define DD 512
#define VV 10000
#define TT 20
#define XX 2560          // E_EMB(512) + E_ENC(2048)
#define NZ 4608          // att2(512) + gatepre(2048) + gates_hh(2048)

typedef __attribute__((ext_vector_type(8))) short bf16x8;
typedef __attribute__((ext_vector_type(4))) float f32x4;

__device__ __forceinline__ unsigned short f2b(float f) {
  unsigned int x = __float_as_uint(f);
  x += 0x7fff + ((x >> 16) & 1);          // RNE
  return (unsigned short)(x >> 16);
}
__device__ __forceinline__ float b2f(unsigned short u) {
  return __uint_as_float(((unsigned int)u) << 16);
}
__device__ __forceinline__ void gload16(const void* g, void* l) {
  __builtin_amdgcn_global_load_lds(
      (const __attribute__((address_space(1))) unsigned int*)g,
      (__attribute__((address_space(3))) unsigned int*)l, 16, 0, 0);
}

// -------------------------------- preamble ---------------------------------

__global__ void k_order(const int* __restrict__ cap_len,
                        int* __restrict__ order, int* __restrict__ declen) {
  __shared__ int len[BB];
  int i = threadIdx.x;
  len[i] = cap_len[i];
  __syncthreads();
  int key = (64 - len[i]) * 64 + i;      // descending len, stable
  int rank = 0;
  for (int j = 0; j < BB; ++j) {
    int kj = (64 - len[j]) * 64 + j;
    rank += (kj < key);
  }
  order[rank] = i;
  declen[rank] = len[i] - 1;
}

// gather-sort encoder to bf16 + mean (fp32)
__global__ __launch_bounds__(256) void k_enc_conv(
    const float* __restrict__ enc, const int* __restrict__ order,
    unsigned short* __restrict__ enc_s, float* __restrict__ mean) {
  const int b = blockIdx.x;
  const int e = blockIdx.y * 256 + threadIdx.x;
  const float* src = enc + ((size_t)order[b] * PP) * EE + e;
  unsigned short* dst = enc_s + ((size_t)b * PP) * EE + e;
  float s = 0.f;
#pragma unroll 4
  for (int p = 0; p < PP; ++p) {
    float v = src[(size_t)p * EE];
    s += v;
    dst[(size_t)p * EE] = f2b(v);
  }
  mean[(size_t)b * EE + e] = s * (1.0f / PP);
}

__global__ __launch_bounds__(256) void k_h0c0(
    const float* __restrict__ mean, const float* __restrict__ hW,
    const float* __restrict__ hb, const float* __restrict__ cW,
    const float* __restrict__ cb, unsigned short* __restrict__ h0,
    float* __restrict__ c0) {
  int b = blockIdx.x;
  __shared__ float m[EE];
  for (int e = threadIdx.x; e < EE; e += 256) m[e] = mean[(size_t)b * EE + e];
  __syncthreads();
  for (int d = threadIdx.x; d < DD; d += 256) {
    const float4* wr = (const float4*)(hW + (size_t)d * EE);
    const float4* wc = (const float4*)(cW + (size_t)d * EE);
    float sh = 0.f, sc = 0.f;
    for (int e4 = 0; e4 < EE / 4; ++e4) {
      float4 mv = *(const float4*)&m[e4 * 4];
      float4 wv = wr[e4];
      sh += mv.x * wv.x + mv.y * wv.y + mv.z * wv.z + mv.w * wv.w;
      float4 cv = wc[e4];
      sc += mv.x * cv.x + mv.y * cv.y + mv.z * cv.z + mv.w * cv.w;
    }
    h0[(size_t)b * DD + d] = f2b(sh + hb[d]);
    c0[(size_t)b * DD + d] = sc + cb[d];
  }
}

// bulk f32 -> bf16 (8 elems / thread)
__global__ __launch_bounds__(256) void k_f2b8(const float* __restrict__ src,
                                              unsigned short* __restrict__ dst,
                                              int n8) {
  int i = blockIdx.x * 256 + threadIdx.x;
  if (i >= n8) return;
  float4 a = ((const float4*)src)[2 * i];
  float4 c = ((const float4*)src)[2 * i + 1];
  union { unsigned short u[8]; uint4 v; } o;
  o.u[0] = f2b(a.x); o.u[1] = f2b(a.y); o.u[2] = f2b(a.z); o.u[3] = f2b(a.w);
  o.u[4] = f2b(c.x); o.u[5] = f2b(c.y); o.u[6] = f2b(c.z); o.u[7] = f2b(c.w);
  ((uint4*)dst)[i] = o.v;
}

// ------------------------- big MFMA GEMM (128x128) -------------------------
// C = A(MxK, bf16 row-major) @ B(NxK, bf16 row-major)^T.
// EPI=0: enc_att -> bf16 out [M][512], +bias.
// EPI=1: final fc -> fp32 preds scatter [b][t][v], +bias, masked by declen.
template <int EPI>
__global__ __launch_bounds__(256) void k_gemm_big(
    const unsigned short* __restrict__ A, const unsigned short* __restrict__ B,
    int K, int nt, unsigned short* __restrict__ outb,
    float* __restrict__ outf, const float* __restrict__ bias,
    const int* __restrict__ declen) {
  __shared__ __align__(16) char smem[2][16384];   // A 8KB + B 8KB per buffer
  const int tid = threadIdx.x;
  const int l = tid & 63;
  const int w = tid >> 6;
  const int wr = w >> 1, wc = w & 1;
  const int m0 = blockIdx.x * 128;
  const int n0 = blockIdx.y * 128;
  f32x4 acc[4][4] = {};

  const int srr = l >> 2;     // row-in-chunk 0..15
  const int ssl = l & 3;      // physical 16B slot
  auto stage = [&](int t) {
    char* dst = &smem[t & 1][0];
    const int k0 = t * 32;
#pragma unroll
    for (int q = 0; q < 4; ++q) {
      const int c = w * 4 + q;               // chunk 0..15 (1 KiB each)
      const int rr = (c & 7) * 16 + srr;     // tile row / col 0..127
      const int sg = ssl ^ ((rr >> 1) & 3);  // logical k-slot for this phys slot
      const unsigned short* src;
      if (c < 8) {
        src = A + (size_t)(m0 + rr) * K + k0 + sg * 8;
      } else {
        int gc = n0 + rr;
        if (EPI == 1 && gc >= VV) gc = 0;    // clamp OOB weight rows
        src = B + (size_t)gc * K + k0 + sg * 8;
      }
      gload16(src, dst + c * 1024);          // linear dest, +lane*16 implicit
    }
  };

  stage(0);
  __syncthreads();
  const int ks = l >> 4;
  for (int t = 0; t < nt; ++t) {
    if (t + 1 < nt) stage(t + 1);
    const char* sa = &smem[t & 1][0];
    const char* sbp = sa + 8192;
    bf16x8 ar[4], br[4];
#pragma unroll
    for (int f = 0; f < 4; ++f) {
      const int row = wr * 64 + f * 16 + (l & 15);
      ar[f] = *(const bf16x8*)(sa + row * 64 + ((ks ^ ((row >> 1) & 3)) << 4));
      const int col = wc * 64 + f * 16 + (l & 15);
      br[f] = *(const bf16x8*)(sbp + col * 64 + ((ks ^ ((col >> 1) & 3)) << 4));
    }
#pragma unroll
    for (int fi = 0; fi < 4; ++fi)
#pragma unroll
      for (int fj = 0; fj < 4; ++fj)
        acc[fi][fj] = __builtin_amdgcn_mfma_f32_16x16x32_bf16(
            ar[fi], br[fj], acc[fi][fj], 0, 0, 0);
    __syncthreads();
  }
#pragma unroll
  for (int fi = 0; fi < 4; ++fi) {
    const int grow = m0 + wr * 64 + fi * 16 + (l >> 4) * 4;
#pragma unroll
    for (int fj = 0; fj < 4; ++fj) {
      const int gcol = n0 + wc * 64 + fj * 16 + (l & 15);
      if (EPI == 0) {
        const float bv = bias[gcol];
#pragma unroll
        for (int r = 0; r < 4; ++r)
          outb[(size_t)(grow + r) * AA + gcol] = f2b(acc[fi][fj][r] + bv);
      } else {
        if (gcol < VV) {
          const float bv = bias[gcol];
#pragma unroll
          for (int r = 0; r < 4; ++r) {
            const int m = grow + r;
            const int t_ = m >> 6, b_ = m & 63;
            const float v = (t_ < declen[b_]) ? acc[fi][fj][r] + bv : 0.f;
            outf[((size_t)b_ * TT + t_) * VV + gcol] = v;
          }
        }
      }
    }
  }
}

// ----------------------- skinny MFMA GEMM (M=64) ---------------------------
// out[by][64][N-slice] (fp32) = A(64xK) @ B(NxK)^T over k in [kb, kb+nt*32).
__global__ __launch_bounds__(256) void k_skinny(
    const unsigned short* __restrict__ A, int lda,
    const unsigned short* __restrict__ B, int ldb, int kspan, int nt,
    float* __restrict__ out, int ldo, long sstride) {
  __shared__ __align__(16) char smem[2][8192];    // A 4KB + B 4KB per buffer
  const int tid = threadIdx.x;
  const int l = tid & 63;
  const int w = tid >> 6;
  const int n0 = blockIdx.x * 64;
  const int kb = blockIdx.y * kspan;
  f32x4 acc[4] = {};
  const int srr = l >> 2, ssl = l & 3;
  auto stage = [&](int t) {
    char* dst = &smem[t & 1][0];
    const int k0 = kb + t * 32;
#pragma unroll
    for (int q = 0; q < 2; ++q) {
      const int c = w * 2 + q;               // chunk 0..7
      const int rr = (c & 3) * 16 + srr;     // 0..63
      const int sg = ssl ^ ((rr >> 1) & 3);
      const unsigned short* src = (c < 4)
          ? A + (size_t)rr * lda + k0 + sg * 8
          : B + (size_t)(n0 + rr) * ldb + k0 + sg * 8;
      gload16(src, dst + c * 1024);
    }
  };
  stage(0);
  __syncthreads();
  const int ks = l >> 4;
  for (int t = 0; t < nt; ++t) {
    if (t + 1 < nt) stage(t + 1);
    const char* sa = &smem[t & 1][0];
    bf16x8 ar[4];
#pragma unroll
    for (int f = 0; f < 4; ++f) {
      const int row = f * 16 + (l & 15);
      ar[f] = *(const bf16x8*)(sa + row * 64 + ((ks ^ ((row >> 1) & 3)) << 4));
    }
    const int col = w * 16 + (l & 15);
    bf16x8 br = *(const bf16x8*)(sa + 4096 + col * 64 +
                                 ((ks ^ ((col >> 1) & 3)) << 4));
#pragma unroll
    for (int f = 0; f < 4; ++f)
      acc[f] = __builtin_amdgcn_mfma_f32_16x16x32_bf16(ar[f], br, acc[f],
                                                       0, 0, 0);
    __syncthreads();
  }
  float* ob = out + (size_t)blockIdx.y * sstride;
  const int gcol = n0 + w * 16 + (l & 15);
#pragma unroll
  for (int f = 0; f < 4; ++f) {
    const int grow = f * 16 + (l >> 4) * 4;
#pragma unroll
    for (int r = 0; r < 4; ++r)
      ob[(size_t)(grow + r) * ldo + gcol] = acc[f][r];
  }
}

// ------------------------------ attention ----------------------------------

__global__ __launch_bounds__(256) void k_att(
    const unsigned short* __restrict__ eatt, const float* __restrict__ Z,
    const float* __restrict__ adb, const float* __restrict__ afW,
    const float* __restrict__ afb, const int* __restrict__ declen,
    float* __restrict__ alph, float* __restrict__ alphas, int t) {
  const int b = blockIdx.x;
  __shared__ float att2[AA];
  __shared__ float wf[AA];
  __shared__ float esm[PP];
  __shared__ float red[16];
  for (int a = threadIdx.x; a < AA; a += 256) {
    att2[a] = Z[(size_t)b * NZ + a] + adb[a];
    wf[a] = afW[a];
  }
  __syncthreads();
  const int lane = threadIdx.x & 63;
  const int w = threadIdx.x >> 6;
  for (int p = w; p < PP; p += 4) {
    uint4 v = *(const uint4*)(eatt + ((size_t)(b * PP + p)) * AA + lane * 8);
    const float* a2 = &att2[lane * 8];
    const float* wv = &wf[lane * 8];
    unsigned int uu[4] = {v.x, v.y, v.z, v.w};
    float s = 0.f;
#pragma unroll
    for (int j = 0; j < 4; ++j) {
      float e0 = b2f((unsigned short)(uu[j] & 0xffffu));
      float e1 = b2f((unsigned short)(uu[j] >> 16));
      float u0 = e0 + a2[2 * j];     u0 = u0 > 0.f ? u0 : 0.f;
      float u1 = e1 + a2[2 * j + 1]; u1 = u1 > 0.f ? u1 : 0.f;
      s += u0 * wv[2 * j] + u1 * wv[2 * j + 1];
    }
#pragma unroll
    for (int off = 32; off; off >>= 1) s += __shfl_xor(s, off);
    if (lane == 0) esm[p] = s + afb[0];
  }
  __syncthreads();
  float v = (threadIdx.x < PP) ? esm[threadIdx.x] : -3.4e38f;
  float m = v;
#pragma unroll
  for (int off = 32; off; off >>= 1) m = fmaxf(m, __shfl_xor(m, off));
  if (lane == 0) red[w] = m;
  __syncthreads();
  m = fmaxf(fmaxf(red[0], red[1]), fmaxf(red[2], red[3]));
  float ex = (threadIdx.x < PP) ? __expf(v - m) : 0.f;
  float ssum = ex;
#pragma unroll
  for (int off = 32; off; off >>= 1) ssum += __shfl_xor(ssum, off);
  if (lane == 0) red[8 + w] = ssum;
  __syncthreads();
  float tot = red[8] + red[9] + red[10] + red[11];
  if (threadIdx.x < PP) {
    float a_ = ex / tot;
    alph[(size_t)b * PP + threadIdx.x] = a_;
    bool act = t < declen[b];
    alphas[((size_t)b * TT + t) * PP + threadIdx.x] = act ? a_ : 0.f;
  }
}

// ctx (bf16 enc) + gate + x assembly
__global__ __launch_bounds__(256) void k_ctx(
    const unsigned short* __restrict__ enc_s, const float* __restrict__ alph,
    const float* __restrict__ Z, const float* __restrict__ sb,
    const float* __restrict__ embW, const int* __restrict__ cap,
    const int* __restrict__ order, unsigned short* __restrict__ x, int t) {
  const int b = blockIdx.x;
  __shared__ float al[PP];
  for (int p = threadIdx.x; p < PP; p += 256) al[p] = alph[(size_t)b * PP + p];
  __syncthreads();
  const int e0 = threadIdx.x * 8;
  float acc[8] = {};
  const unsigned short* ep = enc_s + ((size_t)b * PP) * EE + e0;
#pragma unroll 4
  for (int p = 0; p < PP; ++p) {
    uint4 v = *(const uint4*)(ep + (size_t)p * EE);
    const float ap = al[p];
    unsigned int uu[4] = {v.x, v.y, v.z, v.w};
#pragma unroll
    for (int j = 0; j < 4; ++j) {
      acc[2 * j]     += ap * b2f((unsigned short)(uu[j] & 0xffffu));
      acc[2 * j + 1] += ap * b2f((unsigned short)(uu[j] >> 16));
    }
  }
  const float* zg = Z + (size_t)b * NZ + AA + e0;
  float4 z0 = *(const float4*)zg, z1 = *(const float4*)(zg + 4);
  float4 s0 = *(const float4*)(sb + e0), s1 = *(const float4*)(sb + e0 + 4);
  float gz[8] = {z0.x + s0.x, z0.y + s0.y, z0.z + s0.z, z0.w + s0.w,
                 z1.x + s1.x, z1.y + s1.y, z1.z + s1.z, z1.w + s1.w};
  union { unsigned short u[8]; uint4 v; } o;
#pragma unroll
  for (int j = 0; j < 8; ++j) {
    float g = 1.f / (1.f + __expf(-gz[j]));
    o.u[j] = f2b(g * acc[j]);
  }
  *(uint4*)(x + (size_t)b * XX + AA + e0) = o.v;
  if (threadIdx.x < 64) {
    const int tok = cap[order[b] * 21 + t];
    const int e = threadIdx.x * 8;
    const float* es = embW + (size_t)tok * 512 + e;
    float4 a0 = *(const float4*)es, a1 = *(const float4*)(es + 4);
    union { unsigned short u[8]; uint4 v; } m_;
    m_.u[0] = f2b(a0.x); m_.u[1] = f2b(a0.y);
    m_.u[2] = f2b(a0.z); m_.u[3] = f2b(a0.w);
    m_.u[4] = f2b(a1.x); m_.u[5] = f2b(a1.y);
    m_.u[6] = f2b(a1.z); m_.u[7] = f2b(a1.w);
    *(uint4*)(x + (size_t)b * XX + e) = m_.v;
  }
}

// ------------------------------- LSTM cell ---------------------------------

__global__ __launch_bounds__(256) void k_cell(
    const float* __restrict__ Z, const float* __restrict__ Gp,
    const float* __restrict__ bih, const float* __restrict__ bhh,
    const float* __restrict__ cin, float* __restrict__ cout,
    unsigned short* __restrict__ hout) {
  const int idx = blockIdx.x * 256 + threadIdx.x;   // b*512 + d
  const int b = idx >> 9, d = idx & 511;
  float g4[4];
#pragma unroll
  for (int q = 0; q < 4; ++q) {
    const int j = q * 512 + d;
    float s = bih[j] + bhh[j] + Z[(size_t)b * NZ + 2560 + j];
#pragma unroll
    for (int sp = 0; sp < 4; ++sp)
      s += Gp[((size_t)sp * BB + b) * 2048 + j];
    g4[q] = s;
  }
  const float ig = 1.f / (1.f + __expf(-g4[0]));
  const float fg = 1.f / (1.f + __expf(-g4[1]));
  const float gg = tanhf(g4[2]);
  const float og = 1.f / (1.f + __expf(-g4[3]));
  const float c = fg * cin[idx] + ig * gg;
  const float h = og * tanhf(c);
  cout[idx] = c;
  hout[idx] = f2b(h);
}

// ------------------------------ launch -------------------------------------

extern "C" void kernel_launch(void* const* d_in, const int* in_sizes, int n_in,
                              void* d_out, int out_size, void* d_ws,
                              size_t ws_size, hipStream_t stream) {
  (void)in_sizes; (void)n_in; (void)out_size; (void)ws_size;
  const float* enc  = (const float*)d_in[0];
  const float* embW = (const float*)d_in[1];
  const float* hW   = (const float*)d_in[2];
  const float* hb   = (const float*)d_in[3];
  const float* cW   = (const float*)d_in[4];
  const float* cb   = (const float*)d_in[5];
  const float* aeW  = (const float*)d_in[6];
  const float* aeb  = (const float*)d_in[7];
  const float* adW  = (const float*)d_in[8];
  const float* adb  = (const float*)d_in[9];
  const float* afW  = (const float*)d_in[10];
  const float* afb  = (const float*)d_in[11];
  const float* sW   = (const float*)d_in[12];
  const float* sb   = (const float*)d_in[13];
  const float* Wih  = (const float*)d_in[14];
  const float* Whh  = (const float*)d_in[15];
  const float* bih  = (const float*)d_in[16];
  const float* bhh  = (const float*)d_in[17];
  const float* fcW  = (const float*)d_in[18];
  const float* fcb  = (const float*)d_in[19];
  const int*   cap  = (const int*)d_in[20];
  const int*   capl = (const int*)d_in[21];

  char* p = (char*)d_ws;
  int* order  = (int*)p;            p += 256;
  int* declen = (int*)p;            p += 256;
  float* mean = (float*)p;          p += (size_t)BB * EE * 4;        // 512 KB
  float* cbuf = (float*)p;          p += 2 * (size_t)BB * DD * 4;    // 256 KB
  float* Z    = (float*)p;          p += (size_t)BB * NZ * 4;        // 1.2 MB
  float* Gp   = (float*)p;          p += 4 * (size_t)BB * 2048 * 4;  // 2 MB
  float* alph = (float*)p;          p += (size_t)BB * PP * 4;        // 50 KB
  unsigned short* x     = (unsigned short*)p; p += (size_t)BB * XX * 2;
  unsigned short* h_all = (unsigned short*)p; p += (size_t)(TT + 1) * BB * DD * 2;
  unsigned short* aeWb  = (unsigned short*)p; p += (size_t)AA * EE * 2;
  unsigned short* Wzb   = (unsigned short*)p; p += (size_t)NZ * DD * 2;
  unsigned short* Wihb  = (unsigned short*)p; p += (size_t)2048 * XX * 2;
  unsigned short* fcWb  = (unsigned short*)p; p += (size_t)VV * DD * 2;
  unsigned short* eattb = (unsigned short*)p; p += (size_t)BB * PP * AA * 2;
  unsigned short* enc_s = (unsigned short*)p; p += (size_t)BB * PP * EE * 2;
  // total ws ~98 MB

  float* preds  = (float*)d_out;                        // [64][20][10000]
  float* alphas = preds + (size_t)BB * TT * VV;         // [64][20][196]

  k_order<<<1, 64, 0, stream>>>(capl, order, declen);
  k_enc_conv<<<dim3(BB, EE / 256), 256, 0, stream>>>(enc, order, enc_s, mean);
  k_h0c0<<<BB, 256, 0, stream>>>(mean, hW, hb, cW, cb, h_all, cbuf);
  k_f2b8<<<512,  256, 0, stream>>>(aeW, aeWb, AA * EE / 8);
  k_f2b8<<<128,  256, 0, stream>>>(adW, Wzb, 512 * 512 / 8);
  k_f2b8<<<512,  256, 0, stream>>>(sW,  Wzb + 512 * 512, 2048 * 512 / 8);
  k_f2b8<<<512,  256, 0, stream>>>(Whh, Wzb + 2560 * 512, 2048 * 512 / 8);
  k_f2b8<<<2560, 256, 0, stream>>>(Wih, Wihb, 2048 * XX / 8);
  k_f2b8<<<2500, 256, 0, stream>>>(fcW, fcWb, VV * 512 / 8);
  // enc_att: M=12544, N=512, K=2048
  k_gemm_big<0><<<dim3((BB * PP) / 128, AA / 128), 256, 0, stream>>>(
      enc_s, aeWb, EE, EE / 32, eattb, nullptr, aeb, nullptr);

  for (int t = 0; t < TT; ++t) {
    // S1: Z[64][4608] = h @ [att_dec_W | sig_W | lstm_Whh]^T, K=512
    k_skinny<<<dim3(NZ / 64, 1), 256, 0, stream>>>(
        h_all + (size_t)t * BB * DD, 512, Wzb, 512, 0, 16, Z, NZ, 0);
    k_att<<<BB, 256, 0, stream>>>(eattb, Z, adb, afW, afb, declen, alph,
                                  alphas, t);
    k_ctx<<<BB, 256, 0, stream>>>(enc_s, alph, Z, sb, embW, cap, order, x, t);
    // S4: Gp[4][64][2048] = x @ lstm_Wih^T, K=2560 split 4x640
    k_skinny<<<dim3(2048 / 64, 4), 256, 0, stream>>>(
        x, XX, Wihb, XX, 640, 20, Gp, 2048, (long)BB * 2048);
    k_cell<<<(BB * DD) / 256, 256, 0, stream>>>(
        Z, Gp, bih, bhh, cbuf + (size_t)(t & 1) * BB * DD,
        cbuf + (size_t)((t + 1) & 1) * BB * DD,
        h_all + (size_t)(t + 1) * BB * DD);
  }
  // preds: M=1280 (=20*64 h states), N=10000, K=512
  k_gemm_big<1><<<dim3(10, 79), 256, 0, stream>>>(
      h_all + (size_t)BB * DD, fcWb, 512, 16, nullptr, preds, fcb, declen);
}

// Round 3
// 1419.034 us; speedup vs baseline: 2.3975x; 1.4862x over previous
//
#include <hip/hip_runtime.h>
#include <hip/hip_bf16.h>
#include <math.h>

// ---------------------------------------------------------------------------
// Show-Attend-Tell LSTM decoder, round 3.
// Changes vs round 2 (profile: k_h0c0 295us latency-bound, Occ 3%):
//   - h0/c0 via bf16 MFMA (k_skinny over stacked [hW;cW]) + tiny combine
//   - k_att + k_ctx fused into k_attctx (512 thr), alpha stays in LDS
//   - S1 split-K 2 (144 blocks), S4 split-K 8 (256 blocks)
// ---------------------------------------------------------------------------

#define BB 64
#define PP 196
#define EE 2048
#define AA 512
#define DD 512
#define VV 10000
#define TT 20
#define XX 2560          // E_EMB(512) + E_ENC(2048)
#define NZ 4608          // att2(512) + gatepre(2048) + gates_hh(2048)
#define S1S 2
#define S4S 8

typedef __attribute__((ext_vector_type(8))) short bf16x8;
typedef __attribute__((ext_vector_type(4))) float f32x4;

__device__ __forceinline__ unsigned short f2b(float f) {
  unsigned int x = __float_as_uint(f);
  x += 0x7fff + ((x >> 16) & 1);          // RNE
  return (unsigned short)(x >> 16);
}
__device__ __forceinline__ float b2f(unsigned short u) {
  return __uint_as_float(((unsigned int)u) << 16);
}
__device__ __forceinline__ void gload16(const void* g, void* l) {
  __builtin_amdgcn_global_load_lds(
      (const __attribute__((address_space(1))) unsigned int*)g,
      (__attribute__((address_space(3))) unsigned int*)l, 16, 0, 0);
}

// -------------------------------- preamble ---------------------------------

__global__ void k_order(const int* __restrict__ cap_len,
                        int* __restrict__ order, int* __restrict__ declen) {
  __shared__ int len[BB];
  int i = threadIdx.x;
  len[i] = cap_len[i];
  __syncthreads();
  int key = (64 - len[i]) * 64 + i;      // descending len, stable
  int rank = 0;
  for (int j = 0; j < BB; ++j) {
    int kj = (64 - len[j]) * 64 + j;
    rank += (kj < key);
  }
  order[rank] = i;
  declen[rank] = len[i] - 1;
}

// gather-sort encoder to bf16 + bf16 mean
__global__ __launch_bounds__(256) void k_enc_conv(
    const float* __restrict__ enc, const int* __restrict__ order,
    unsigned short* __restrict__ enc_s, unsigned short* __restrict__ meanb) {
  const int b = blockIdx.x;
  const int e = blockIdx.y * 256 + threadIdx.x;
  const float* src = enc + ((size_t)order[b] * PP) * EE + e;
  unsigned short* dst = enc_s + ((size_t)b * PP) * EE + e;
  float s = 0.f;
#pragma unroll 4
  for (int p = 0; p < PP; ++p) {
    float v = src[(size_t)p * EE];
    s += v;
    dst[(size_t)p * EE] = f2b(v);
  }
  meanb[(size_t)b * EE + e] = f2b(s * (1.0f / PP));
}

// bulk f32 -> bf16 (8 elems / thread)
__global__ __launch_bounds__(256) void k_f2b8(const float* __restrict__ src,
                                              unsigned short* __restrict__ dst,
                                              int n8) {
  int i = blockIdx.x * 256 + threadIdx.x;
  if (i >= n8) return;
  float4 a = ((const float4*)src)[2 * i];
  float4 c = ((const float4*)src)[2 * i + 1];
  union { unsigned short u[8]; uint4 v; } o;
  o.u[0] = f2b(a.x); o.u[1] = f2b(a.y); o.u[2] = f2b(a.z); o.u[3] = f2b(a.w);
  o.u[4] = f2b(c.x); o.u[5] = f2b(c.y); o.u[6] = f2b(c.z); o.u[7] = f2b(c.w);
  ((uint4*)dst)[i] = o.v;
}

// combine Hp partials -> h0 (bf16) and c0 (fp32)
__global__ __launch_bounds__(256) void k_h0c0_fin(
    const float* __restrict__ Hp, const float* __restrict__ hb,
    const float* __restrict__ cb, unsigned short* __restrict__ h0,
    float* __restrict__ c0) {
  const int idx = blockIdx.x * 256 + threadIdx.x;   // 0..65535
  const int b = idx >> 10, n = idx & 1023;
  float s = 0.f;
#pragma unroll
  for (int sp = 0; sp < 8; ++sp)
    s += Hp[((size_t)sp * BB + b) * 1024 + n];
  if (n < DD) h0[(size_t)b * DD + n] = f2b(s + hb[n]);
  else        c0[(size_t)b * DD + (n - DD)] = s + cb[n - DD];
}

// ------------------------- big MFMA GEMM (128x128) -------------------------
// C = A(MxK, bf16 row-major) @ B(NxK, bf16 row-major)^T.
// EPI=0: enc_att -> bf16 out [M][512], +bias.
// EPI=1: final fc -> fp32 preds scatter [b][t][v], +bias, masked by declen.
template <int EPI>
__global__ __launch_bounds__(256) void k_gemm_big(
    const unsigned short* __restrict__ A, const unsigned short* __restrict__ B,
    int K, int nt, unsigned short* __restrict__ outb,
    float* __restrict__ outf, const float* __restrict__ bias,
    const int* __restrict__ declen) {
  __shared__ __align__(16) char smem[2][16384];   // A 8KB + B 8KB per buffer
  const int tid = threadIdx.x;
  const int l = tid & 63;
  const int w = tid >> 6;
  const int wr = w >> 1, wc = w & 1;
  const int m0 = blockIdx.x * 128;
  const int n0 = blockIdx.y * 128;
  f32x4 acc[4][4] = {};

  const int srr = l >> 2;     // row-in-chunk 0..15
  const int ssl = l & 3;      // physical 16B slot
  auto stage = [&](int t) {
    char* dst = &smem[t & 1][0];
    const int k0 = t * 32;
#pragma unroll
    for (int q = 0; q < 4; ++q) {
      const int c = w * 4 + q;               // chunk 0..15 (1 KiB each)
      const int rr = (c & 7) * 16 + srr;     // tile row / col 0..127
      const int sg = ssl ^ ((rr >> 1) & 3);  // logical k-slot for this slot
      const unsigned short* src;
      if (c < 8) {
        src = A + (size_t)(m0 + rr) * K + k0 + sg * 8;
      } else {
        int gc = n0 + rr;
        if (EPI == 1 && gc >= VV) gc = 0;    // clamp OOB weight rows
        src = B + (size_t)gc * K + k0 + sg * 8;
      }
      gload16(src, dst + c * 1024);
    }
  };

  stage(0);
  __syncthreads();
  const int ks = l >> 4;
  for (int t = 0; t < nt; ++t) {
    if (t + 1 < nt) stage(t + 1);
    const char* sa = &smem[t & 1][0];
    const char* sbp = sa + 8192;
    bf16x8 ar[4], br[4];
#pragma unroll
    for (int f = 0; f < 4; ++f) {
      const int row = wr * 64 + f * 16 + (l & 15);
      ar[f] = *(const bf16x8*)(sa + row * 64 + ((ks ^ ((row >> 1) & 3)) << 4));
      const int col = wc * 64 + f * 16 + (l & 15);
      br[f] = *(const bf16x8*)(sbp + col * 64 + ((ks ^ ((col >> 1) & 3)) << 4));
    }
#pragma unroll
    for (int fi = 0; fi < 4; ++fi)
#pragma unroll
      for (int fj = 0; fj < 4; ++fj)
        acc[fi][fj] = __builtin_amdgcn_mfma_f32_16x16x32_bf16(
            ar[fi], br[fj], acc[fi][fj], 0, 0, 0);
    __syncthreads();
  }
#pragma unroll
  for (int fi = 0; fi < 4; ++fi) {
    const int grow = m0 + wr * 64 + fi * 16 + (l >> 4) * 4;
#pragma unroll
    for (int fj = 0; fj < 4; ++fj) {
      const int gcol = n0 + wc * 64 + fj * 16 + (l & 15);
      if (EPI == 0) {
        const float bv = bias[gcol];
#pragma unroll
        for (int r = 0; r < 4; ++r)
          outb[(size_t)(grow + r) * AA + gcol] = f2b(acc[fi][fj][r] + bv);
      } else {
        if (gcol < VV) {
          const float bv = bias[gcol];
#pragma unroll
          for (int r = 0; r < 4; ++r) {
            const int m = grow + r;
            const int t_ = m >> 6, b_ = m & 63;
            const float v = (t_ < declen[b_]) ? acc[fi][fj][r] + bv : 0.f;
            outf[((size_t)b_ * TT + t_) * VV + gcol] = v;
          }
        }
      }
    }
  }
}

// ----------------------- skinny MFMA GEMM (M=64) ---------------------------
// out[by][64][N-slice] (fp32) = A(64xK) @ B(NxK)^T over k in [kb, kb+nt*32).
__global__ __launch_bounds__(256) void k_skinny(
    const unsigned short* __restrict__ A, int lda,
    const unsigned short* __restrict__ B, int ldb, int kspan, int nt,
    float* __restrict__ out, int ldo, long sstride) {
  __shared__ __align__(16) char smem[2][8192];    // A 4KB + B 4KB per buffer
  const int tid = threadIdx.x;
  const int l = tid & 63;
  const int w = tid >> 6;
  const int n0 = blockIdx.x * 64;
  const int kb = blockIdx.y * kspan;
  f32x4 acc[4] = {};
  const int srr = l >> 2, ssl = l & 3;
  auto stage = [&](int t) {
    char* dst = &smem[t & 1][0];
    const int k0 = kb + t * 32;
#pragma unroll
    for (int q = 0; q < 2; ++q) {
      const int c = w * 2 + q;               // chunk 0..7
      const int rr = (c & 3) * 16 + srr;     // 0..63
      const int sg = ssl ^ ((rr >> 1) & 3);
      const unsigned short* src = (c < 4)
          ? A + (size_t)rr * lda + k0 + sg * 8
          : B + (size_t)(n0 + rr) * ldb + k0 + sg * 8;
      gload16(src, dst + c * 1024);
    }
  };
  stage(0);
  __syncthreads();
  const int ks = l >> 4;
  for (int t = 0; t < nt; ++t) {
    if (t + 1 < nt) stage(t + 1);
    const char* sa = &smem[t & 1][0];
    bf16x8 ar[4];
#pragma unroll
    for (int f = 0; f < 4; ++f) {
      const int row = f * 16 + (l & 15);
      ar[f] = *(const bf16x8*)(sa + row * 64 + ((ks ^ ((row >> 1) & 3)) << 4));
    }
    const int col = w * 16 + (l & 15);
    bf16x8 br = *(const bf16x8*)(sa + 4096 + col * 64 +
                                 ((ks ^ ((col >> 1) & 3)) << 4));
#pragma unroll
    for (int f = 0; f < 4; ++f)
      acc[f] = __builtin_amdgcn_mfma_f32_16x16x32_bf16(ar[f], br, acc[f],
                                                       0, 0, 0);
    __syncthreads();
  }
  float* ob = out + (size_t)blockIdx.y * sstride;
  const int gcol = n0 + w * 16 + (l & 15);
#pragma unroll
  for (int f = 0; f < 4; ++f) {
    const int grow = f * 16 + (l >> 4) * 4;
#pragma unroll
    for (int r = 0; r < 4; ++r)
      ob[(size_t)(grow + r) * ldo + gcol] = acc[f][r];
  }
}

// ----------------- fused attention + context + x assembly ------------------
// One 512-thread block per b: att2 -> e-scores -> softmax -> ctx/gate/x.
__global__ __launch_bounds__(512) void k_attctx(
    const unsigned short* __restrict__ eatt, const unsigned short* __restrict__ enc_s,
    const float* __restrict__ Zp, const float* __restrict__ adb,
    const float* __restrict__ afW, const float* __restrict__ afb,
    const float* __restrict__ sb, const float* __restrict__ embW,
    const int* __restrict__ cap, const int* __restrict__ order,
    const int* __restrict__ declen, unsigned short* __restrict__ x,
    float* __restrict__ alphas, int t) {
  const int b = blockIdx.x;
  const int tid = threadIdx.x;
  __shared__ float att2[AA];
  __shared__ float wf[AA];
  __shared__ float esm[PP];
  __shared__ float al[PP];
  __shared__ float red[16];
  for (int a = tid; a < AA; a += 512) {
    att2[a] = Zp[(size_t)b * NZ + a] + Zp[((size_t)BB + b) * NZ + a] + adb[a];
    wf[a] = afW[a];
  }
  __syncthreads();
  const int lane = tid & 63;
  const int w = tid >> 6;           // 0..7
  for (int p = w; p < PP; p += 8) {
    uint4 v = *(const uint4*)(eatt + ((size_t)(b * PP + p)) * AA + lane * 8);
    const float* a2 = &att2[lane * 8];
    const float* wv = &wf[lane * 8];
    unsigned int uu[4] = {v.x, v.y, v.z, v.w};
    float s = 0.f;
#pragma unroll
    for (int j = 0; j < 4; ++j) {
      float e0 = b2f((unsigned short)(uu[j] & 0xffffu));
      float e1 = b2f((unsigned short)(uu[j] >> 16));
      float u0 = e0 + a2[2 * j];     u0 = u0 > 0.f ? u0 : 0.f;
      float u1 = e1 + a2[2 * j + 1]; u1 = u1 > 0.f ? u1 : 0.f;
      s += u0 * wv[2 * j] + u1 * wv[2 * j + 1];
    }
#pragma unroll
    for (int off = 32; off; off >>= 1) s += __shfl_xor(s, off);
    if (lane == 0) esm[p] = s + afb[0];
  }
  __syncthreads();
  // softmax over 196 (threads 0..195 hold values)
  float v = (tid < PP) ? esm[tid] : -3.4e38f;
  float m = v;
#pragma unroll
  for (int off = 32; off; off >>= 1) m = fmaxf(m, __shfl_xor(m, off));
  if (lane == 0) red[w] = m;
  __syncthreads();
  m = red[0];
#pragma unroll
  for (int q = 1; q < 8; ++q) m = fmaxf(m, red[q]);
  float ex = (tid < PP) ? __expf(v - m) : 0.f;
  float ssum = ex;
#pragma unroll
  for (int off = 32; off; off >>= 1) ssum += __shfl_xor(ssum, off);
  if (lane == 0) red[8 + w] = ssum;
  __syncthreads();
  float tot = red[8];
#pragma unroll
  for (int q = 1; q < 8; ++q) tot += red[8 + q];
  if (tid < PP) {
    float a_ = ex / tot;
    al[tid] = a_;
    alphas[((size_t)b * TT + t) * PP + tid] = (t < declen[b]) ? a_ : 0.f;
  }
  __syncthreads();
  // ctx over e: 512 threads x 4 e each
  const int e0 = tid * 4;
  float acc[4] = {};
  const unsigned short* ep = enc_s + ((size_t)b * PP) * EE + e0;
#pragma unroll 4
  for (int p = 0; p < PP; ++p) {
    uint2 vv = *(const uint2*)(ep + (size_t)p * EE);
    const float ap = al[p];
    acc[0] += ap * b2f((unsigned short)(vv.x & 0xffffu));
    acc[1] += ap * b2f((unsigned short)(vv.x >> 16));
    acc[2] += ap * b2f((unsigned short)(vv.y & 0xffffu));
    acc[3] += ap * b2f((unsigned short)(vv.y >> 16));
  }
  const float* zg0 = Zp + (size_t)b * NZ + AA + e0;
  const float* zg1 = Zp + ((size_t)BB + b) * NZ + AA + e0;
  float4 z0 = *(const float4*)zg0;
  float4 z1 = *(const float4*)zg1;
  float4 s0 = *(const float4*)(sb + e0);
  float gz[4] = {z0.x + z1.x + s0.x, z0.y + z1.y + s0.y,
                 z0.z + z1.z + s0.z, z0.w + z1.w + s0.w};
  union { unsigned short u[4]; uint2 v; } o;
#pragma unroll
  for (int j = 0; j < 4; ++j) {
    float g = 1.f / (1.f + __expf(-gz[j]));
    o.u[j] = f2b(g * acc[j]);
  }
  *(uint2*)(x + (size_t)b * XX + AA + e0) = o.v;
  if (tid < 64) {
    const int tok = cap[order[b] * 21 + t];
    const int e = tid * 8;
    const float* es = embW + (size_t)tok * 512 + e;
    float4 a0 = *(const float4*)es, a1 = *(const float4*)(es + 4);
    union { unsigned short u[8]; uint4 v; } m_;
    m_.u[0] = f2b(a0.x); m_.u[1] = f2b(a0.y);
    m_.u[2] = f2b(a0.z); m_.u[3] = f2b(a0.w);
    m_.u[4] = f2b(a1.x); m_.u[5] = f2b(a1.y);
    m_.u[6] = f2b(a1.z); m_.u[7] = f2b(a1.w);
    *(uint4*)(x + (size_t)b * XX + e) = m_.v;
  }
}

// ------------------------------- LSTM cell ---------------------------------

__global__ __launch_bounds__(256) void k_cell(
    const float* __restrict__ Zp, const float* __restrict__ Gp,
    const float* __restrict__ bih, const float* __restrict__ bhh,
    const float* __restrict__ cin, float* __restrict__ cout,
    unsigned short* __restrict__ hout) {
  const int idx = blockIdx.x * 256 + threadIdx.x;   // b*512 + d
  const int b = idx >> 9, d = idx & 511;
  float g4[4];
#pragma unroll
  for (int q = 0; q < 4; ++q) {
    const int j = q * 512 + d;
    float s = bih[j] + bhh[j] + Zp[(size_t)b * NZ + 2560 + j] +
              Zp[((size_t)BB + b) * NZ + 2560 + j];
#pragma unroll
    for (int sp = 0; sp < S4S; ++sp)
      s += Gp[((size_t)sp * BB + b) * 2048 + j];
    g4[q] = s;
  }
  const float ig = 1.f / (1.f + __expf(-g4[0]));
  const float fg = 1.f / (1.f + __expf(-g4[1]));
  const float gg = tanhf(g4[2]);
  const float og = 1.f / (1.f + __expf(-g4[3]));
  const float c = fg * cin[idx] + ig * gg;
  const float h = og * tanhf(c);
  cout[idx] = c;
  hout[idx] = f2b(h);
}

// ------------------------------ launch -------------------------------------

extern "C" void kernel_launch(void* const* d_in, const int* in_sizes, int n_in,
                              void* d_out, int out_size, void* d_ws,
                              size_t ws_size, hipStream_t stream) {
  (void)in_sizes; (void)n_in; (void)out_size; (void)ws_size;
  const float* enc  = (const float*)d_in[0];
  const float* embW = (const float*)d_in[1];
  const float* hW   = (const float*)d_in[2];
  const float* hb   = (const float*)d_in[3];
  const float* cW   = (const float*)d_in[4];
  const float* cb   = (const float*)d_in[5];
  const float* aeW  = (const float*)d_in[6];
  const float* aeb  = (const float*)d_in[7];
  const float* adW  = (const float*)d_in[8];
  const float* adb  = (const float*)d_in[9];
  const float* afW  = (const float*)d_in[10];
  const float* afb  = (const float*)d_in[11];
  const float* sW   = (const float*)d_in[12];
  const float* sb   = (const float*)d_in[13];
  const float* Wih  = (const float*)d_in[14];
  const float* Whh  = (const float*)d_in[15];
  const float* bih  = (const float*)d_in[16];
  const float* bhh  = (const float*)d_in[17];
  const float* fcW  = (const float*)d_in[18];
  const float* fcb  = (const float*)d_in[19];
  const int*   cap  = (const int*)d_in[20];
  const int*   capl = (const int*)d_in[21];

  char* p = (char*)d_ws;
  int* order  = (int*)p;            p += 256;
  int* declen = (int*)p;            p += 256;
  float* cbuf = (float*)p;          p += 2 * (size_t)BB * DD * 4;      // 256 KB
  float* Zp   = (float*)p;          p += (size_t)S1S * BB * NZ * 4;    // 2.4 MB
  float* Gp   = (float*)p;          p += (size_t)S4S * BB * 2048 * 4;  // 4 MB
  float* Hp   = (float*)p;          p += (size_t)8 * BB * 1024 * 4;    // 2 MB
  unsigned short* meanb = (unsigned short*)p; p += (size_t)BB * EE * 2;
  unsigned short* x     = (unsigned short*)p; p += (size_t)BB * XX * 2;
  unsigned short* h_all = (unsigned short*)p; p += (size_t)(TT + 1) * BB * DD * 2;
  unsigned short* aeWb  = (unsigned short*)p; p += (size_t)AA * EE * 2;
  unsigned short* Wzb   = (unsigned short*)p; p += (size_t)NZ * DD * 2;
  unsigned short* Whcb  = (unsigned short*)p; p += (size_t)1024 * EE * 2;
  unsigned short* Wihb  = (unsigned short*)p; p += (size_t)2048 * XX * 2;
  unsigned short* fcWb  = (unsigned short*)p; p += (size_t)VV * DD * 2;
  unsigned short* eattb = (unsigned short*)p; p += (size_t)BB * PP * AA * 2;
  unsigned short* enc_s = (unsigned short*)p; p += (size_t)BB * PP * EE * 2;
  // total ws ~103 MB

  float* preds  = (float*)d_out;                        // [64][20][10000]
  float* alphas = preds + (size_t)BB * TT * VV;         // [64][20][196]

  k_order<<<1, 64, 0, stream>>>(capl, order, declen);
  k_enc_conv<<<dim3(BB, EE / 256), 256, 0, stream>>>(enc, order, enc_s, meanb);
  k_f2b8<<<512,  256, 0, stream>>>(aeW, aeWb, AA * EE / 8);
  k_f2b8<<<128,  256, 0, stream>>>(adW, Wzb, 512 * 512 / 8);
  k_f2b8<<<512,  256, 0, stream>>>(sW,  Wzb + 512 * 512, 2048 * 512 / 8);
  k_f2b8<<<512,  256, 0, stream>>>(Whh, Wzb + 2560 * 512, 2048 * 512 / 8);
  k_f2b8<<<512,  256, 0, stream>>>(hW,  Whcb, 512 * EE / 8);
  k_f2b8<<<512,  256, 0, stream>>>(cW,  Whcb + 512 * EE, 512 * EE / 8);
  k_f2b8<<<2560, 256, 0, stream>>>(Wih, Wihb, 2048 * XX / 8);
  k_f2b8<<<2500, 256, 0, stream>>>(fcW, fcWb, VV * 512 / 8);
  // h0/c0: [64][1024] = meanb @ [hW;cW]^T, K=2048, 8 splits
  k_skinny<<<dim3(1024 / 64, 8), 256, 0, stream>>>(
      meanb, EE, Whcb, EE, 256, 8, Hp, 1024, (long)BB * 1024);
  k_h0c0_fin<<<256, 256, 0, stream>>>(Hp, hb, cb, h_all, cbuf);
  // enc_att: M=12544, N=512, K=2048
  k_gemm_big<0><<<dim3((BB * PP) / 128, AA / 128), 256, 0, stream>>>(
      enc_s, aeWb, EE, EE / 32, eattb, nullptr, aeb, nullptr);

  for (int t = 0; t < TT; ++t) {
    // S1: Zp[2][64][4608] = h @ [att_dec_W | sig_W | lstm_Whh]^T, K=512
    k_skinny<<<dim3(NZ / 64, S1S), 256, 0, stream>>>(
        h_all + (size_t)t * BB * DD, 512, Wzb, 512, 256, 8, Zp, NZ,
        (long)BB * NZ);
    k_attctx<<<BB, 512, 0, stream>>>(eattb, enc_s, Zp, adb, afW, afb, sb,
                                     embW, cap, order, declen, x, alphas, t);
    // S4: Gp[8][64][2048] = x @ lstm_Wih^T, K=2560 split 8x320
    k_skinny<<<dim3(2048 / 64, S4S), 256, 0, stream>>>(
        x, XX, Wihb, XX, 320, 10, Gp, 2048, (long)BB * 2048);
    k_cell<<<(BB * DD) / 256, 256, 0, stream>>>(
        Zp, Gp, bih, bhh, cbuf + (size_t)(t & 1) * BB * DD,
        cbuf + (size_t)((t + 1) & 1) * BB * DD,
        h_all + (size_t)(t + 1) * BB * DD);
  }
  // preds: M=1280 (=20*64 h states), N=10000, K=512
  k_gemm_big<1><<<dim3(10, 79), 256, 0, stream>>>(
      h_all + (size_t)BB * DD, fcWb, 512, 16, nullptr, preds, fcb, declen);
}